// Round 10
// baseline (361.436 us; speedup 1.0000x reference)
//
#include <hip/hip_runtime.h>
#include <hip/hip_bf16.h>

#define BATCH     262144
#define TPB       256
#define GRID_MAIN 2048          // BATCH / 128 samples-per-block
#define EPS1      2.0e-4f
#define EPS2      4.0e-4f

typedef __attribute__((ext_vector_type(8))) short bf16x8;
typedef __attribute__((ext_vector_type(4))) float f32x4;

union FragU { unsigned int u[4]; bf16x8 v; int4 i4; };

__device__ __forceinline__ unsigned short f2bf(float x) {
    __hip_bfloat16 h = __float2bfloat16(x);     // RNE
    unsigned short u; __builtin_memcpy(&u, &h, 2); return u;
}
__device__ __forceinline__ float bf2f(unsigned short u) {
    unsigned int w = ((unsigned int)u) << 16;
    float f; __builtin_memcpy(&f, &w, 4); return f;
}
__device__ __forceinline__ unsigned int fold16(unsigned long long b) {
    b |= b >> 32; b |= b >> 16;
    return (unsigned int)(b & 0xFFFFull);
}

// ---------------------------------------------------------------------------
// Prep: build MFMA A-fragment arrays (split hi/lo bf16), bias C-frags, and
// fp32 transposes (W2T, W1T32) for the in-wave exact repair.
// ---------------------------------------------------------------------------
__global__ void lnn_prep(const float* __restrict__ W1, const float* __restrict__ b1,
                         const float* __restrict__ W2, const float* __restrict__ b2,
                         const float* __restrict__ W3,
                         unsigned int* __restrict__ W1AH, unsigned int* __restrict__ W1AL,
                         unsigned int* __restrict__ W2AH, unsigned int* __restrict__ W2AL,
                         unsigned int* __restrict__ VA,   unsigned int* __restrict__ W4A,
                         float* __restrict__ B1A, float* __restrict__ B2A,
                         float* __restrict__ W2T, float* __restrict__ W1T32) {
    const int g = blockIdx.x * blockDim.x + threadIdx.x;   // 16384 threads

    for (int t = g; t < 8 * 64 * 4; t += 16384) {          // [idx][lane][r]
        const int idx = t >> 8, lane = (t >> 2) & 63, r = t & 3;
        const int jt = idx >> 1, kc = idx & 1;
        const int row = lane & 15;
        const int k0 = kc * 32 + (lane >> 4) * 8 + 2 * r;  // even element
        {   // G1 A = W1^T
            const int j = jt * 16 + row;
            const float v0 = W1[(k0 + 0) * 64 + j], v1 = W1[(k0 + 1) * 64 + j];
            const unsigned short h0 = f2bf(v0), h1 = f2bf(v1);
            const unsigned short l0 = f2bf(v0 - bf2f(h0)), l1 = f2bf(v1 - bf2f(h1));
            W1AH[t] = (unsigned)h0 | ((unsigned)h1 << 16);
            W1AL[t] = (unsigned)l0 | ((unsigned)l1 << 16);
        }
        {   // G2 A = W2^T
            const int j2 = jt * 16 + row;
            const float v0 = W2[(k0 + 0) * 64 + j2], v1 = W2[(k0 + 1) * 64 + j2];
            const unsigned short h0 = f2bf(v0), h1 = f2bf(v1);
            const unsigned short l0 = f2bf(v0 - bf2f(h0)), l1 = f2bf(v1 - bf2f(h1));
            W2AH[t] = (unsigned)h0 | ((unsigned)h1 << 16);
            W2AL[t] = (unsigned)l0 | ((unsigned)l1 << 16);
        }
        {   // G3 A = V^T: A[j, j2] = w3[j2] * W2[j][j2]
            const int j = jt * 16 + row;
            const float v0 = W3[k0 + 0] * W2[j * 64 + (k0 + 0)];
            const float v1 = W3[k0 + 1] * W2[j * 64 + (k0 + 1)];
            VA[t] = (unsigned)f2bf(v0) | ((unsigned)f2bf(v1) << 16);
        }
        if (idx < 4) {  // G4 A = -W1 rows k<32
            const int mt = idx >> 1;
            const int k = mt * 16 + row;
            const float v0 = -W1[k * 64 + (k0 + 0)], v1 = -W1[k * 64 + (k0 + 1)];
            W4A[t] = (unsigned)f2bf(v0) | ((unsigned)f2bf(v1) << 16);
        }
    }
    for (int t = g; t < 4 * 64 * 4; t += 16384) {          // bias frags (C layout)
        const int jt = t >> 8, lane = (t >> 2) & 63, r = t & 3;
        const int j = jt * 16 + (lane >> 4) * 4 + r;
        B1A[t] = b1[j];
        B2A[t] = b2[j];
    }
    for (int t = g; t < 64 * 64; t += 16384) {             // repair: W2T[j2][j]
        const int i = t >> 6, j = t & 63;
        W2T[j * 64 + i] = W2[i * 64 + j];
    }
    for (int t = g; t < 64 * 32; t += 16384) {             // repair: W1T32[i][k]
        const int i = t >> 5, k = t & 31;
        W1T32[i * 32 + k] = W1[k * 64 + i];
    }
}

// ---------------------------------------------------------------------------
// Main: transposed MFMA pipeline, 4 waves x 32 samples per block.
//   G1: Z1^T = W1^T x X^T (split bf16 x3) -> m1, h -> LDS(HB)
//   G2: Z2^T = W2^T x H^T (split bf16 x3) -> M2  -> LDS(MU, aliases HB)
//   G3: T^T  = V^T x M2^T                 -> U = m1.*T -> LDS(MU)
//   G4: OUT^T= (-W1k) x U                 -> predicated store
// Near-zero z cells flag their sample in a per-wave uniform mask; flagged
// samples are recomputed EXACTLY (fp32 sgemm-order chains) in-wave. No
// atomics, no extra kernel. HB/MU aliased: every MU write data-depends on
// every HB read via the MFMA accumulators, so ordering is enforced.
// ---------------------------------------------------------------------------
__global__ __launch_bounds__(TPB) void lnn_mfma(
        const float* __restrict__ X,
        const unsigned int* __restrict__ W1AH, const unsigned int* __restrict__ W1AL,
        const unsigned int* __restrict__ W2AH, const unsigned int* __restrict__ W2AL,
        const unsigned int* __restrict__ VA,   const unsigned int* __restrict__ W4A,
        const float* __restrict__ B1A, const float* __restrict__ B2A,
        const float* __restrict__ W1, const float* __restrict__ b1,
        const float* __restrict__ W2, const float* __restrict__ b2,
        const float* __restrict__ W3, const float* __restrict__ W2T,
        const float* __restrict__ W1T32,
        float* __restrict__ out) {
    __shared__ unsigned int SMEM[4][64 * 33];              // 33,792 B total

    const int tid = threadIdx.x;
    const int w  = tid >> 6;
    const int l  = tid & 63;
    const int lr = l & 15;
    const int lg = l >> 4;
    const int s0 = blockIdx.x * 128 + w * 32;

    unsigned int* __restrict__ HBw = SMEM[w];              // packed (hh | hl<<16)
    unsigned short* __restrict__ MUw = (unsigned short*)SMEM[w];  // M2 then U

    const f32x4 zz = {0.f, 0.f, 0.f, 0.f};
    f32x4 acc[4][2];
    unsigned int flagmask = 0u;

    // ================= G1 =================
#pragma unroll
    for (int jt = 0; jt < 4; ++jt)
#pragma unroll
        for (int nt = 0; nt < 2; ++nt) acc[jt][nt] = zz;

#pragma unroll
    for (int kc = 0; kc < 2; ++kc) {
        FragU bh[2], bl[2];
#pragma unroll
        for (int nt = 0; nt < 2; ++nt) {
            const float* xp = X + (size_t)(s0 + nt * 16 + lr) * 64 + kc * 32 + lg * 8;
            const float4 x0 = reinterpret_cast<const float4*>(xp)[0];
            const float4 x1 = reinterpret_cast<const float4*>(xp)[1];
            const float xs[8] = {x0.x, x0.y, x0.z, x0.w, x1.x, x1.y, x1.z, x1.w};
#pragma unroll
            for (int r = 0; r < 4; ++r) {
                const unsigned short h0 = f2bf(xs[2 * r]),     h1 = f2bf(xs[2 * r + 1]);
                const unsigned short q0 = f2bf(xs[2 * r] - bf2f(h0));
                const unsigned short q1 = f2bf(xs[2 * r + 1] - bf2f(h1));
                bh[nt].u[r] = (unsigned)h0 | ((unsigned)h1 << 16);
                bl[nt].u[r] = (unsigned)q0 | ((unsigned)q1 << 16);
            }
        }
#pragma unroll
        for (int jt = 0; jt < 4; ++jt) {
            FragU ah, al;
            ah.i4 = reinterpret_cast<const int4*>(W1AH)[(jt * 2 + kc) * 64 + l];
            al.i4 = reinterpret_cast<const int4*>(W1AL)[(jt * 2 + kc) * 64 + l];
#pragma unroll
            for (int nt = 0; nt < 2; ++nt) {
                acc[jt][nt] = __builtin_amdgcn_mfma_f32_16x16x32_bf16(al.v, bh[nt].v, acc[jt][nt], 0, 0, 0);
                acc[jt][nt] = __builtin_amdgcn_mfma_f32_16x16x32_bf16(ah.v, bl[nt].v, acc[jt][nt], 0, 0, 0);
                acc[jt][nt] = __builtin_amdgcn_mfma_f32_16x16x32_bf16(ah.v, bh[nt].v, acc[jt][nt], 0, 0, 0);
            }
        }
    }

    unsigned int m1 = 0u;
    {
        bool f0 = false, f1 = false;
#pragma unroll
        for (int jt = 0; jt < 4; ++jt) {
            const float4 bv = reinterpret_cast<const float4*>(B1A)[jt * 64 + l];
            const float bb[4] = {bv.x, bv.y, bv.z, bv.w};
#pragma unroll
            for (int nt = 0; nt < 2; ++nt) {
                const int sc = nt * 16 + lr;
#pragma unroll
                for (int r = 0; r < 4; ++r) {
                    const float z = acc[jt][nt][r] + bb[r];
                    if (z > 0.f) m1 |= 1u << (jt * 8 + nt * 4 + r);
                    const bool c = __builtin_fabsf(z) < EPS1;
                    if (nt == 0) f0 |= c; else f1 |= c;
                    const float h = fmaxf(z, 0.f);
                    const unsigned short hh = f2bf(h);
                    const unsigned short hl = f2bf(h - bf2f(hh));
                    HBw[(jt * 16 + lg * 4 + r) * 33 + sc] = (unsigned)hh | ((unsigned)hl << 16);
                }
            }
        }
        flagmask |= fold16(__ballot(f0));
        flagmask |= fold16(__ballot(f1)) << 16;
    }

    // ================= G2 =================
#pragma unroll
    for (int jt = 0; jt < 4; ++jt)
#pragma unroll
        for (int nt = 0; nt < 2; ++nt) acc[jt][nt] = zz;

#pragma unroll
    for (int kc = 0; kc < 2; ++kc) {
        FragU bh[2], bl[2];
#pragma unroll
        for (int nt = 0; nt < 2; ++nt) {
            const int sc = nt * 16 + lr;
#pragma unroll
            for (int r = 0; r < 4; ++r) {
                const int i0 = kc * 32 + lg * 8 + 2 * r;
                const unsigned int ue = HBw[i0 * 33 + sc];
                const unsigned int uo = HBw[(i0 + 1) * 33 + sc];
                bh[nt].u[r] = (ue & 0xFFFFu) | (uo << 16);
                bl[nt].u[r] = (ue >> 16) | (uo & 0xFFFF0000u);
            }
        }
#pragma unroll
        for (int jt = 0; jt < 4; ++jt) {
            FragU ah, al;
            ah.i4 = reinterpret_cast<const int4*>(W2AH)[(jt * 2 + kc) * 64 + l];
            al.i4 = reinterpret_cast<const int4*>(W2AL)[(jt * 2 + kc) * 64 + l];
#pragma unroll
            for (int nt = 0; nt < 2; ++nt) {
                acc[jt][nt] = __builtin_amdgcn_mfma_f32_16x16x32_bf16(al.v, bh[nt].v, acc[jt][nt], 0, 0, 0);
                acc[jt][nt] = __builtin_amdgcn_mfma_f32_16x16x32_bf16(ah.v, bl[nt].v, acc[jt][nt], 0, 0, 0);
                acc[jt][nt] = __builtin_amdgcn_mfma_f32_16x16x32_bf16(ah.v, bh[nt].v, acc[jt][nt], 0, 0, 0);
            }
        }
    }

    {
        bool f0 = false, f1 = false;
#pragma unroll
        for (int jt = 0; jt < 4; ++jt) {
            const float4 bv = reinterpret_cast<const float4*>(B2A)[jt * 64 + l];
            const float bb[4] = {bv.x, bv.y, bv.z, bv.w};
#pragma unroll
            for (int nt = 0; nt < 2; ++nt) {
                const int sc = nt * 16 + lr;
#pragma unroll
                for (int r = 0; r < 4; ++r) {
                    const float z = acc[jt][nt][r] + bb[r];
                    MUw[(jt * 16 + lg * 4 + r) * 33 + sc] =
                        (z > 0.f) ? (unsigned short)0x3F80u : (unsigned short)0u;
                    const bool c = __builtin_fabsf(z) < EPS2;
                    if (nt == 0) f0 |= c; else f1 |= c;
                }
            }
        }
        flagmask |= fold16(__ballot(f0));
        flagmask |= fold16(__ballot(f1)) << 16;
    }

    // ================= G3 =================
#pragma unroll
    for (int jt = 0; jt < 4; ++jt)
#pragma unroll
        for (int nt = 0; nt < 2; ++nt) acc[jt][nt] = zz;

#pragma unroll
    for (int kc = 0; kc < 2; ++kc) {
        FragU bm[2];
#pragma unroll
        for (int nt = 0; nt < 2; ++nt) {
            const int sc = nt * 16 + lr;
#pragma unroll
            for (int r = 0; r < 4; ++r) {
                const int i0 = kc * 32 + lg * 8 + 2 * r;
                const unsigned int ue = MUw[i0 * 33 + sc];
                const unsigned int uo = MUw[(i0 + 1) * 33 + sc];
                bm[nt].u[r] = ue | (uo << 16);
            }
        }
#pragma unroll
        for (int jt = 0; jt < 4; ++jt) {
            FragU av;
            av.i4 = reinterpret_cast<const int4*>(VA)[(jt * 2 + kc) * 64 + l];
#pragma unroll
            for (int nt = 0; nt < 2; ++nt)
                acc[jt][nt] = __builtin_amdgcn_mfma_f32_16x16x32_bf16(av.v, bm[nt].v, acc[jt][nt], 0, 0, 0);
        }
    }
#pragma unroll
    for (int jt = 0; jt < 4; ++jt)
#pragma unroll
        for (int nt = 0; nt < 2; ++nt) {
            const int sc = nt * 16 + lr;
#pragma unroll
            for (int r = 0; r < 4; ++r) {
                const float uv = ((m1 >> (jt * 8 + nt * 4 + r)) & 1u) ? acc[jt][nt][r] : 0.f;
                MUw[(jt * 16 + lg * 4 + r) * 33 + sc] = f2bf(uv);
            }
        }

    // ================= G4 =================
    f32x4 acc4[2][2];
#pragma unroll
    for (int mt = 0; mt < 2; ++mt)
#pragma unroll
        for (int nt = 0; nt < 2; ++nt) acc4[mt][nt] = zz;

#pragma unroll
    for (int kc = 0; kc < 2; ++kc) {
        FragU bu[2];
#pragma unroll
        for (int nt = 0; nt < 2; ++nt) {
            const int sc = nt * 16 + lr;
#pragma unroll
            for (int r = 0; r < 4; ++r) {
                const int i0 = kc * 32 + lg * 8 + 2 * r;
                const unsigned int ue = MUw[i0 * 33 + sc];
                const unsigned int uo = MUw[(i0 + 1) * 33 + sc];
                bu[nt].u[r] = ue | (uo << 16);
            }
        }
#pragma unroll
        for (int mt = 0; mt < 2; ++mt) {
            FragU a4;
            a4.i4 = reinterpret_cast<const int4*>(W4A)[(mt * 2 + kc) * 64 + l];
#pragma unroll
            for (int nt = 0; nt < 2; ++nt)
                acc4[mt][nt] = __builtin_amdgcn_mfma_f32_16x16x32_bf16(a4.v, bu[nt].v, acc4[mt][nt], 0, 0, 0);
        }
    }
#pragma unroll
    for (int mt = 0; mt < 2; ++mt)
#pragma unroll
        for (int nt = 0; nt < 2; ++nt) {
            const bool keep = !((flagmask >> (nt * 16 + lr)) & 1u);
#pragma unroll
            for (int r = 0; r < 4; ++r)
                if (keep)
                    out[(size_t)(s0 + nt * 16 + lr) * 32 + mt * 16 + lg * 4 + r] = acc4[mt][nt][r];
        }

    // ============ in-wave exact repair (uniform loop, ~1-2 samples/wave) ====
    unsigned int fm = flagmask;
    while (fm) {
        const int sc = __ffs(fm) - 1; fm &= fm - 1;
        const int s = s0 + sc;
        const float xv = X[(size_t)s * 64 + l];

        float z1 = 0.f;
#pragma unroll 1
        for (int i = 0; i < 64; ++i)
            z1 = fmaf(__shfl(xv, i), W1[i * 64 + l], z1);   // ascending, single acc
        z1 += b1[l];                                         // one rounded add
        const unsigned long long m1r = __ballot(z1 > 0.f);
        const float h = fmaxf(z1, 0.f);

        float z2 = 0.f;
#pragma unroll 1
        for (int i = 0; i < 64; ++i)
            z2 = fmaf(__shfl(h, i), W2[i * 64 + l], z2);
        z2 += b2[l];
        const unsigned long long m2r = __ballot(z2 > 0.f);

        float tv = 0.f;
#pragma unroll 1
        for (int j2 = 0; j2 < 64; ++j2)
            if ((m2r >> j2) & 1ull) tv = fmaf(W3[j2], W2T[j2 * 64 + l], tv);
        const float uv = ((m1r >> l) & 1ull) ? tv : 0.f;

        float o = 0.f;
#pragma unroll 1
        for (int i = 0; i < 64; ++i) {
            const float wv = (l < 32) ? W1T32[i * 32 + l] : 0.f;
            o = fmaf(__shfl(uv, i), wv, o);
        }
        if (l < 32) out[(size_t)s * 32 + l] = -o;
    }
}

extern "C" void kernel_launch(void* const* d_in, const int* in_sizes, int n_in,
                              void* d_out, int out_size, void* d_ws, size_t ws_size,
                              hipStream_t stream) {
    const float* X  = (const float*)d_in[0];
    const float* W1 = (const float*)d_in[1];
    const float* b1 = (const float*)d_in[2];
    const float* W2 = (const float*)d_in[3];
    const float* b2 = (const float*)d_in[4];
    const float* W3 = (const float*)d_in[5];
    // d_in[6] = b3: does not affect gradients.
    float* out = (float*)d_out;

    char* ws = (char*)d_ws;
    unsigned int* W1AH = (unsigned int*)(ws + 0);        //  8 KB
    unsigned int* W1AL = (unsigned int*)(ws + 8192);     //  8 KB
    unsigned int* W2AH = (unsigned int*)(ws + 16384);    //  8 KB
    unsigned int* W2AL = (unsigned int*)(ws + 24576);    //  8 KB
    unsigned int* VAp  = (unsigned int*)(ws + 32768);    //  8 KB
    unsigned int* W4Ap = (unsigned int*)(ws + 40960);    //  4 KB
    float*        B1A  = (float*)(ws + 45056);           //  4 KB
    float*        B2A  = (float*)(ws + 49152);           //  4 KB
    float*        W2T  = (float*)(ws + 53248);           // 16 KB
    float*        W1T32= (float*)(ws + 69632);           //  8 KB

    lnn_prep<<<64, 256, 0, stream>>>(W1, b1, W2, b2, W3,
                                     W1AH, W1AL, W2AH, W2AL, VAp, W4Ap,
                                     B1A, B2A, W2T, W1T32);
    lnn_mfma<<<GRID_MAIN, TPB, 0, stream>>>(X, W1AH, W1AL, W2AH, W2AL, VAp, W4Ap,
                                            B1A, B2A, W1, b1, W2, b2, W3, W2T, W1T32,
                                            out);
}